// Round 5
// baseline (225.571 us; speedup 1.0000x reference)
//
#include <hip/hip_runtime.h>

// GlobalGatedUpdater, round 8: nontemporal streaming stores (R7 compile-fixed).
//
// R7 failed to compile: __builtin_nontemporal_* rejects HIP_vector_type<float,4>*.
// Fix: native clang ext_vector_type(4) (bit-identical) for all NT accesses.
//
// Theory (unchanged): store rate pinned at 1.8-2.2 TB/s across R3-R6 variants
// (burst 1-20 KB, streams 1-16, traffic 218-410 MB) while harness fill does
// 6.8 TB/s on the same buffer -> categorical write-path gap. Plain stores
// write-allocate in L2; 205 MB write-once stream churns 32 MB L2 through
// allocate->dirty->evict; eviction drain caps rate. NT stores bypass L2.

#define DIM 64
#define SEGS (DIM / 4)          // 16 float4 per row
#define BLOCK 256
#define KF 2                    // float4 per thread
#define TILE (BLOCK * KF)       // 512 float4 = 8 KB per block
#define NROWS (TILE / SEGS)     // 32 rows per block-tile

typedef float vf4 __attribute__((ext_vector_type(4)));

template <int CB>  // CB = compile-time B (0 = runtime fallback)
__global__ __launch_bounds__(BLOCK) void ggu_nt(
    const int* __restrict__ nodes,        // (B*n)
    const float4* __restrict__ feat,      // (B*n, SEGS)
    const vf4* __restrict__ emb,          // (items, SEGS)
    const float* __restrict__ alpha,      // (items)
    vf4* __restrict__ out,                // (B, items, SEGS)
    int items, int n, int Brt)
{
    const int B = (CB > 0) ? CB : Brt;
    const size_t rowsF4 = (size_t)items * SEGS;          // 800000 float4 / graph
    const size_t base   = (size_t)blockIdx.x * TILE;     // float4 offset in graph
    const int row0      = (int)(base / SEGS);
    const int tid       = threadIdx.x;

    extern __shared__ int smem[];
    int* lastj = smem;                                   // B*NROWS entries
    unsigned* tmaskp = (unsigned*)(smem + B * NROWS);    // touched-graph bitmask

    for (int t = tid; t < B * NROWS; t += BLOCK) lastj[t] = -1;
    if (tid == 0) *tmaskp = 0u;
    __syncthreads();
    const int total = B * n;                             // 800
    for (int t = tid; t < total; t += BLOCK) {
        const int local = nodes[t] - row0;
        if ((unsigned)local < (unsigned)NROWS) {
            const int b = t / n;
            atomicMax(&lastj[b * NROWS + local], t);     // t monotone in j per b
            atomicOr(tmaskp, 1u << b);
        }
    }
    __syncthreads();
    const unsigned tm = *tmaskp;                         // uniform broadcast

    // Load this block's 8 KB emb slice ONCE (streaming, no L2 pollution).
    vf4 v[KF];
    const vf4* e = emb + base;
    #pragma unroll
    for (int k = 0; k < KF; ++k) {
        const size_t off = (size_t)(k * BLOCK + tid);
        v[k] = (base + off < rowsF4) ? __builtin_nontemporal_load(e + off)
                                     : (vf4){0.0f, 0.0f, 0.0f, 0.0f};
    }

    // B contiguous 8 KB bursts, start graph rotated per block.
    for (int bb = 0; bb < B; ++bb) {
        int b;
        if (CB == 16) {
            b = (blockIdx.x + bb) & 15;
        } else {
            b = (int)(blockIdx.x % B) + bb;
            if (b >= B) b -= B;
        }
        vf4* ob = out + (size_t)b * rowsF4 + base;
        if (!((tm >> b) & 1u)) {
            // Common path: pure broadcast of the register slice.
            #pragma unroll
            for (int k = 0; k < KF; ++k) {
                const size_t off = (size_t)(k * BLOCK + tid);
                if (base + off < rowsF4)
                    __builtin_nontemporal_store(v[k], ob + off);
            }
        } else {
            #pragma unroll
            for (int k = 0; k < KF; ++k) {
                const size_t off = (size_t)(k * BLOCK + tid);
                if (base + off >= rowsF4) continue;
                vf4 t4 = v[k];
                const int ioff = k * BLOCK + tid;
                const int jl = lastj[b * NROWS + (ioff >> 4)];
                if (jl >= 0) {                           // rare: ~0.1% of rows
                    const int row = row0 + (ioff >> 4);
                    const float a = alpha[row];
                    const float4 f = feat[(size_t)jl * SEGS + (ioff & (SEGS - 1))];
                    const float om = 1.0f - a;
                    t4.x = om * t4.x + a * f.x;
                    t4.y = om * t4.y + a * f.y;
                    t4.z = om * t4.z + a * f.z;
                    t4.w = om * t4.w + a * f.w;
                }
                __builtin_nontemporal_store(t4, ob + off);
            }
        }
    }
}

extern "C" void kernel_launch(void* const* d_in, const int* in_sizes, int n_in,
                              void* d_out, int out_size, void* d_ws, size_t ws_size,
                              hipStream_t stream) {
    const int*   nodes = (const int*)d_in[0];
    const float* feat  = (const float*)d_in[1];
    const float* emb   = (const float*)d_in[2];
    const float* alpha = (const float*)d_in[3];

    const int items = in_sizes[3];                 // 50000
    const int B     = out_size / (items * DIM);    // 16
    const int n     = in_sizes[0] / B;             // 50

    const size_t rowsF4 = (size_t)items * SEGS;    // 800000
    const unsigned grid = (unsigned)((rowsF4 + TILE - 1) / TILE);  // 1563
    const size_t lds_bytes = (size_t)(B * NROWS + 1) * sizeof(int); // ~2.1 KB

    if (B == 16) {
        ggu_nt<16><<<grid, BLOCK, lds_bytes, stream>>>(
            nodes, (const float4*)feat, (const vf4*)emb, alpha,
            (vf4*)d_out, items, n, B);
    } else {
        ggu_nt<0><<<grid, BLOCK, lds_bytes, stream>>>(
            nodes, (const float4*)feat, (const vf4*)emb, alpha,
            (vf4*)d_out, items, n, B);
    }
}